// Round 7
// baseline (1344.774 us; speedup 1.0000x reference)
//
#include <hip/hip_runtime.h>

#define HN 8
#define DH 256
#define HID 2048
#define BB 4
#define SS 2048
#define TT (BB*SS)
#define NQKV 2560      // (H + 2*KV) * D
#define NSLOTS 16384

typedef unsigned short u16;
typedef unsigned int u32;
typedef __bf16 bf16x8 __attribute__((ext_vector_type(8)));
typedef float f32x4 __attribute__((ext_vector_type(4)));
typedef u16 u16x4 __attribute__((ext_vector_type(4)));
typedef u16 u16x8 __attribute__((ext_vector_type(8)));

__device__ __forceinline__ u16 f2bf(float f) {
    u32 u = __builtin_bit_cast(u32, f);
    u = u + 0x7fffu + ((u >> 16) & 1u);   // RNE; inputs are never NaN
    return (u16)(u >> 16);
}
__device__ __forceinline__ float bf2f(u16 h) {
    u32 u = ((u32)h) << 16;
    return __builtin_bit_cast(float, u);
}
__device__ __forceinline__ void gload_lds16(const void* g, void* l) {
    __builtin_amdgcn_global_load_lds((__attribute__((address_space(1))) void*)g,
                                     (__attribute__((address_space(3))) void*)l,
                                     16, 0, 0);
}
__device__ __forceinline__ u32 cvtpk_bf16(float a, float b) {
    u32 r;
    asm("v_cvt_pk_bf16_f32 %0, %1, %2" : "=v"(r) : "v"(a), "v"(b));
    return r;
}

// ---------------- fp32 -> bf16 conversion ----------------
__global__ __launch_bounds__(256) void cvt_f32_bf16(const float* __restrict__ in,
                                                    u16* __restrict__ out, long n) {
    long i = ((long)blockIdx.x * blockDim.x + threadIdx.x) * 4;
    long stride = (long)gridDim.x * blockDim.x * 4;
    for (; i < n; i += stride) {
        float4 v = *(const float4*)(in + i);
        u16x4 o4;
        o4[0] = f2bf(v.x); o4[1] = f2bf(v.y); o4[2] = f2bf(v.z); o4[3] = f2bf(v.w);
        *(u16x4*)(out + i) = o4;
    }
}

// ---------------- NT GEMM: C[M,N] = A[M,K] * B[N,K]^T  (m97 recipe) ----------------
template<int OUTBF>
__global__ __launch_bounds__(256) void gemm_nt(const u16* __restrict__ A, const u16* __restrict__ B,
                                               void* __restrict__ C, int M, int N, int K) {
    __shared__ u16 As[128 * 32];
    __shared__ u16 Bs[128 * 32];
    const int tid = threadIdx.x;
    const int lane = tid & 63, w = tid >> 6;
    const int quad = lane >> 4, m16 = lane & 15;
    const int wm = w & 1, wn = w >> 1;
    const int r4 = tid >> 2, c8 = (tid & 3) * 8;
    const long arow = (long)blockIdx.x * 128;
    const long brow = (long)blockIdx.y * 128;

    f32x4 acc[4][4];
#pragma unroll
    for (int i = 0; i < 4; i++)
#pragma unroll
        for (int j = 0; j < 4; j++) acc[i][j] = (f32x4){0.f, 0.f, 0.f, 0.f};

    const u16* Ag = A + (arow + r4) * (long)K + c8;
    const u16* Bg = B + (brow + r4) * (long)K + c8;

    for (int k0 = 0; k0 < K; k0 += 32) {
        __syncthreads();
        gload_lds16(Ag + k0,                 (char*)As + tid * 16);
        gload_lds16(Ag + 64l * K + k0,       (char*)As + 4096 + tid * 16);
        gload_lds16(Bg + k0,                 (char*)Bs + tid * 16);
        gload_lds16(Bg + 64l * K + k0,       (char*)Bs + 4096 + tid * 16);
        __syncthreads();
        bf16x8 af[4], bfr[4];
#pragma unroll
        for (int mi = 0; mi < 4; mi++)
            af[mi] = *(const bf16x8*)(As + (wm * 64 + mi * 16 + m16) * 32 + quad * 8);
#pragma unroll
        for (int ni = 0; ni < 4; ni++)
            bfr[ni] = *(const bf16x8*)(Bs + (wn * 64 + ni * 16 + m16) * 32 + quad * 8);
#pragma unroll
        for (int mi = 0; mi < 4; mi++)
#pragma unroll
            for (int ni = 0; ni < 4; ni++)
                acc[mi][ni] = __builtin_amdgcn_mfma_f32_16x16x32_bf16(af[mi], bfr[ni], acc[mi][ni], 0, 0, 0);
    }
#pragma unroll
    for (int mi = 0; mi < 4; mi++) {
#pragma unroll
        for (int ni = 0; ni < 4; ni++) {
            long col = brow + wn * 64 + ni * 16 + m16;
#pragma unroll
            for (int r = 0; r < 4; r++) {
                long row = arow + wm * 64 + mi * 16 + quad * 4 + r;
                float v = acc[mi][ni][r];
                if (OUTBF) ((u16*)C)[row * N + col] = f2bf(v);
                else       ((float*)C)[row * N + col] = v;
            }
        }
    }
}

// ---------------- RoPE + cache scatter ----------------
__global__ __launch_bounds__(256) void rope_scatter(u16* __restrict__ qkv, const float* __restrict__ cosb,
        const float* __restrict__ sinb, const int* __restrict__ slots,
        u16* __restrict__ kb, float* __restrict__ kc, float* __restrict__ vc) {
    const int t = blockIdx.x, tid = threadIdx.x;
    const long qbase = (long)t * NQKV;
#pragma unroll
    for (int i = 0; i < 4; i++) {
        int idx = tid + i * 256;            // 0..1023 : 8 heads x 128 pairs
        int head = idx >> 7, d = idx & 127;
        long off = qbase + head * DH + d;
        float q1 = bf2f(qkv[off]), q2 = bf2f(qkv[off + 128]);
        float c = cosb[(long)t * 128 + d], s = sinb[(long)t * 128 + d];
        qkv[off]       = f2bf((q1 * c - q2 * s) * 0.0625f);
        qkv[off + 128] = f2bf((q2 * c + q1 * s) * 0.0625f);
    }
    const int slot = slots[t];
    if (tid < 128) {
        int d = tid;
        long off = qbase + HN * DH + d;
        float k1 = bf2f(qkv[off]), k2 = bf2f(qkv[off + 128]);
        float c = cosb[(long)t * 128 + d], s = sinb[(long)t * 128 + d];
        float kn1 = k1 * c - k2 * s, kn2 = k2 * c + k1 * s;
        kb[(long)t * DH + d]       = f2bf(kn1);
        kb[(long)t * DH + d + 128] = f2bf(kn2);
        kc[(long)slot * DH + d]       = kn1;
        kc[(long)slot * DH + d + 128] = kn2;
    }
    {
        int d = tid;
        vc[(long)slot * DH + d] = bf2f(qkv[qbase + (HN + 1) * DH + d]);
    }
}

// ---------------- V transpose: qkv v-slice -> vbt[b][d][s] (LDS tile transpose) ----------------
__global__ __launch_bounds__(256) void transpose_v(const u16* __restrict__ qkv, u16* __restrict__ vbt) {
    __shared__ u16 Ls[64][66];   // pad 66: odd dword stride spreads the transpose reads
    const int tid = threadIdx.x;
    const int s0 = blockIdx.x * 64, d0 = blockIdx.y * 64, b = blockIdx.z;
    const int lr = tid >> 3, lc = (tid & 7) * 8;
#pragma unroll
    for (int i = 0; i < 2; i++) {
        int s = s0 + i * 32 + lr;
        u16x8 v = *(const u16x8*)(qkv + (long)(b * SS + s) * NQKV + (HN + 1) * DH + d0 + lc);
        *(u16x8*)(&Ls[i * 32 + lr][lc]) = v;
    }
    __syncthreads();
#pragma unroll
    for (int i = 0; i < 2; i++) {
        int d = i * 32 + lr;
        u16x8 v;
#pragma unroll
        for (int e = 0; e < 8; e++) v[e] = Ls[lc + e][d];
        *(u16x8*)(vbt + ((long)b * DH + d0 + d) * SS + s0 + lc) = v;
    }
}

// ---------------- Flash attention (causal, GQA KV=1) ----------------
// Block = (b, h, 64 q rows), 4 waves x 16 rows, kv-tile 32.
// Swapped QK^T (sc = mfma(K, Q)) + permuted K staging: P->PV A-frag is in-lane
// (4 v_cvt_pk_bf16_f32), no LDS round-trip (derivation in R5; ref-verified).
// R7: (a) batch->XCD affinity: grid.x encodes (s,b,t) with XCD = x%8 = 2b+s, so each
// XCD touches ONE batch's kb+vbt = 2 MB < 4 MB L2 -- L2 residency is structural,
// immune to block drift (the R6 failure mode). t-order is LPT (large qb first),
// s-split tile-balanced (248/248 qb-sum per batch).
// (b) V is NOT staged in LDS: PV B-fragments read straight from L2-resident vbt
// (lesson: don't stage what cache-fits). Halves staging + vmcnt + LDS traffic.
// (c) LDS 16 KB -> 6 blocks/CU (launch_bounds cap 85 VGPR, spill-safe).
__global__ __launch_bounds__(256, 6) void flash_attn(const u16* __restrict__ qkv, const u16* __restrict__ kb,
                                                     const u16* __restrict__ vbt, u16* __restrict__ attn) {
    __shared__ u16 Ks[32 * 256];      // 16 KB (row-permuted + granule-swizzled)
    const int tid = threadIdx.x;
    const int lane = tid & 63, w = tid >> 6;
    const int quad = lane >> 4, m16 = lane & 15;
    // decode grid.x = s + 2*b + 8*t  (XCD = x%8 = s+2b, t in [0,16))
    const int xr = blockIdx.x & 7, t = blockIdx.x >> 3;
    const int s_cls = xr & 1, b = xr >> 1;
    const int qb = (t < 8) ? (31 - 2 * t - s_cls) : (2 * (t - 8) + s_cls);   // LPT within class
    const int h = blockIdx.y;
    const int qrow_w = qb * 64 + w * 16;

    // K staging decomposition: LDS row s = i*8 + krow, src row = kv0 + perm(s):
    //   perm(s) = ((i&1)<<4) + ((krow>>2)<<3) + ((i>>1)<<2) + (krow&3)
    const int krow = tid >> 5, kg = tid & 31, kgs = kg ^ krow;
    const int ks_hi = (krow >> 2) << 3, ks_lo = krow & 3;
    const int km7 = m16 & 7;

    bf16x8 aq[8];
    {
        const u16* qp = qkv + (long)(b * SS + qrow_w + m16) * NQKV + h * DH;
#pragma unroll
        for (int ks = 0; ks < 8; ks++)
            aq[ks] = *(const bf16x8*)(qp + ks * 32 + quad * 8);
    }
    f32x4 o[16];
#pragma unroll
    for (int i = 0; i < 16; i++) o[i] = (f32x4){0.f, 0.f, 0.f, 0.f};
    float m_run = -1e30f;   // running max for q row = m16 (row-uniform across quads)
    float l_run = 0.f;      // per-lane partial sum for q row = m16
    const long kvrow0 = (long)b * SS;
    // V base for this lane: row d = m16 (+ nf*16), col granule quad*8 (no swizzle: direct L2)
    const u16* vlane = vbt + ((long)b * DH + m16) * SS + quad * 8;
    const int ntiles = 2 * qb + 2;

    for (int it = 0; it < ntiles; it++) {
        const int kv0 = it * 32;
        __syncthreads();   // all waves done reading previous tile's LDS
#pragma unroll
        for (int i = 0; i < 4; i++) {
            const int srcrow = ((i & 1) << 4) + ks_hi + ((i >> 1) << 2) + ks_lo;  // perm(i*8+krow)
            gload_lds16(kb + (kvrow0 + kv0 + srcrow) * DH + kgs * 8,
                        (char*)Ks + i * 4096 + tid * 16);
        }
        asm volatile("s_waitcnt vmcnt(0)" ::: "memory");
        __syncthreads();   // staging visible to all waves

        if (kv0 <= qrow_w + 15) {   // wave-uniform: skip fully-masked tiles
            // swapped Q K^T : D[kv][q], lane holds q=m16, kv = n*16+quad*4+r (LDS-row space)
            f32x4 sc[2];
            sc[0] = (f32x4){0.f, 0.f, 0.f, 0.f};
            sc[1] = (f32x4){0.f, 0.f, 0.f, 0.f};
            __builtin_amdgcn_s_setprio(1);
#pragma unroll
            for (int ks = 0; ks < 8; ks++)
#pragma unroll
                for (int n = 0; n < 2; n++) {
                    bf16x8 kf = *(const bf16x8*)(Ks + (n * 16 + m16) * 256 + (((ks * 4 + quad) ^ km7) << 3));
                    sc[n] = __builtin_amdgcn_mfma_f32_16x16x32_bf16(kf, aq[ks], sc[n], 0, 0, 0);
                }
            __builtin_amdgcn_s_setprio(0);
            // causal mask: actual kv = kv0 + quad*8 + n*4 + r (perm-staged); q = qrow_w + m16
            if (kv0 >= qb * 64) {
                const int qg = qrow_w + m16;
                const int kvb = kv0 + quad * 8;
#pragma unroll
                for (int n = 0; n < 2; n++)
#pragma unroll
                    for (int r = 0; r < 4; r++)
                        if (kvb + n * 4 + r > qg) sc[n][r] = -1e30f;
            }
            // online softmax, defer-max (thr=8): per-lane 8 values of row q=m16
            float mx = fmaxf(fmaxf(fmaxf(sc[0][0], sc[0][1]), fmaxf(sc[0][2], sc[0][3])),
                             fmaxf(fmaxf(sc[1][0], sc[1][1]), fmaxf(sc[1][2], sc[1][3])));
            if (__any((int)(mx > m_run + 8.f))) {   // slow path: first tile + rare growth
                float mr = fmaxf(mx, __shfl_xor(mx, 16));
                mr = fmaxf(mr, __shfl_xor(mr, 32));
                float mn = fmaxf(m_run, mr);
                float alpha = __expf(m_run - mn);   // row-uniform (for q=m16)
                m_run = mn;
                l_run *= alpha;
                float ar[4];
#pragma unroll
                for (int r = 0; r < 4; r++) ar[r] = __shfl(alpha, quad * 4 + r);  // o rows = quad*4+r
#pragma unroll
                for (int nf = 0; nf < 16; nf++)
#pragma unroll
                    for (int r = 0; r < 4; r++) o[nf][r] *= ar[r];
            }
#pragma unroll
            for (int n = 0; n < 2; n++)
#pragma unroll
                for (int r = 0; r < 4; r++) {
                    float p = __expf(sc[n][r] - m_run);   // bounded by e^8
                    sc[n][r] = p;
                    l_run += p;
                }
            // P -> PV A-frag: in-lane pack (element e = n*4+r matches kv = quad*8+e)
            union { u32 w4[4]; bf16x8 v; } pu;
            pu.w4[0] = cvtpk_bf16(sc[0][0], sc[0][1]);
            pu.w4[1] = cvtpk_bf16(sc[0][2], sc[0][3]);
            pu.w4[2] = cvtpk_bf16(sc[1][0], sc[1][1]);
            pu.w4[3] = cvtpk_bf16(sc[1][2], sc[1][3]);
            // PV: B-fragments straight from L2-resident vbt (no LDS)
            const u16* vt = vlane + kv0;
            __builtin_amdgcn_s_setprio(1);
#pragma unroll
            for (int nf = 0; nf < 16; nf++) {
                bf16x8 vf = *(const bf16x8*)(vt + (long)nf * 16 * SS);
                o[nf] = __builtin_amdgcn_mfma_f32_16x16x32_bf16(pu.v, vf, o[nf], 0, 0, 0);
            }
            __builtin_amdgcn_s_setprio(0);
        }
    }
    // final: reduce per-lane l partials across quads (row q=m16), then bcast to o rows
    l_run += __shfl_xor(l_run, 16);
    l_run += __shfl_xor(l_run, 32);
    float invm = 1.f / l_run;
    float ir[4];
#pragma unroll
    for (int r = 0; r < 4; r++) ir[r] = __shfl(invm, quad * 4 + r);
#pragma unroll
    for (int nf = 0; nf < 16; nf++)
#pragma unroll
        for (int r = 0; r < 4; r++) {
            long row = (long)(b * SS + qrow_w + quad * 4 + r);
            attn[row * (HN * DH) + h * DH + nf * 16 + m16] = f2bf(o[nf][r] * ir[r]);
        }
}

// ---------------- launch ----------------
extern "C" void kernel_launch(void* const* d_in, const int* in_sizes, int n_in,
                              void* d_out, int out_size, void* d_ws, size_t ws_size,
                              hipStream_t stream) {
    (void)in_sizes; (void)n_in; (void)out_size; (void)ws_size;
    const float* hidden = (const float*)d_in[0];
    const float* cosb   = (const float*)d_in[1];
    const float* sinb   = (const float*)d_in[2];
    const int*   slots  = (const int*)d_in[3];
    const float* kc_in  = (const float*)d_in[4];
    const float* vc_in  = (const float*)d_in[5];
    const float* w_qkv  = (const float*)d_in[6];
    const float* w_o    = (const float*)d_in[7];

    float* out    = (float*)d_out;
    float* kc_out = out + (size_t)TT * HID;
    float* vc_out = kc_out + (size_t)NSLOTS * DH;

    char* p = (char*)d_ws;
    u16* hid_b  = (u16*)p;  p += (size_t)TT * HID * 2;     // 33.6 MB
    u16* wqkv_b = (u16*)p;  p += (size_t)NQKV * HID * 2;   // 10.5 MB
    u16* wo_b   = (u16*)p;  p += (size_t)HID * HID * 2;    // 8.4 MB
    u16* kb     = (u16*)p;  p += (size_t)TT * DH * 2;      // 4.2 MB
    u16* vbt    = (u16*)p;  p += (size_t)TT * DH * 2;      // 4.2 MB  [b][d][s]
    u16* attn_b = hid_b;                 // hid_b dead after GEMM1
    u16* qkv_b  = (u16*)d_out;           // out region scratch; dead before GEMM2 writes

    hipMemcpyAsync(kc_out, kc_in, (size_t)NSLOTS * DH * 4, hipMemcpyDeviceToDevice, stream);
    hipMemcpyAsync(vc_out, vc_in, (size_t)NSLOTS * DH * 4, hipMemcpyDeviceToDevice, stream);

    cvt_f32_bf16<<<dim3(2048), dim3(256), 0, stream>>>(hidden, hid_b, (long)TT * HID);
    cvt_f32_bf16<<<dim3(640),  dim3(256), 0, stream>>>(w_qkv, wqkv_b, (long)NQKV * HID);
    cvt_f32_bf16<<<dim3(512),  dim3(256), 0, stream>>>(w_o,   wo_b,   (long)HID * HID);

    gemm_nt<1><<<dim3(TT / 128, NQKV / 128), dim3(256), 0, stream>>>(hid_b, wqkv_b, qkv_b, TT, NQKV, HID);
    rope_scatter<<<dim3(TT), dim3(256), 0, stream>>>(qkv_b, cosb, sinb, slots, kb, kc_out, vc_out);
    transpose_v<<<dim3(SS / 64, DH / 64, BB), dim3(256), 0, stream>>>(qkv_b, vbt);
    flash_attn<<<dim3(4 * 32, HN, 1), dim3(256), 0, stream>>>(qkv_b, kb, vbt, attn_b);
    gemm_nt<0><<<dim3(TT / 128, HID / 128), dim3(256), 0, stream>>>(attn_b, wo_b, out, TT, HID, HID);
}

// Round 8
// 633.412 us; speedup vs baseline: 2.1231x; 2.1231x over previous
//
#include <hip/hip_runtime.h>

#define HN 8
#define DH 256
#define HID 2048
#define BB 4
#define SS 2048
#define TT (BB*SS)
#define NQKV 2560      // (H + 2*KV) * D
#define NSLOTS 16384

typedef unsigned short u16;
typedef unsigned int u32;
typedef __bf16 bf16x8 __attribute__((ext_vector_type(8)));
typedef float f32x4 __attribute__((ext_vector_type(4)));
typedef u16 u16x4 __attribute__((ext_vector_type(4)));
typedef u16 u16x8 __attribute__((ext_vector_type(8)));

__device__ __forceinline__ u16 f2bf(float f) {
    u32 u = __builtin_bit_cast(u32, f);
    u = u + 0x7fffu + ((u >> 16) & 1u);   // RNE; inputs are never NaN
    return (u16)(u >> 16);
}
__device__ __forceinline__ float bf2f(u16 h) {
    u32 u = ((u32)h) << 16;
    return __builtin_bit_cast(float, u);
}
__device__ __forceinline__ void gload_lds16(const void* g, void* l) {
    __builtin_amdgcn_global_load_lds((__attribute__((address_space(1))) void*)g,
                                     (__attribute__((address_space(3))) void*)l,
                                     16, 0, 0);
}
__device__ __forceinline__ u32 cvtpk_bf16(float a, float b) {
    u32 r;
    asm("v_cvt_pk_bf16_f32 %0, %1, %2" : "=v"(r) : "v"(a), "v"(b));
    return r;
}

// ---------------- fp32 -> bf16 conversion ----------------
__global__ __launch_bounds__(256) void cvt_f32_bf16(const float* __restrict__ in,
                                                    u16* __restrict__ out, long n) {
    long i = ((long)blockIdx.x * blockDim.x + threadIdx.x) * 4;
    long stride = (long)gridDim.x * blockDim.x * 4;
    for (; i < n; i += stride) {
        float4 v = *(const float4*)(in + i);
        u16x4 o4;
        o4[0] = f2bf(v.x); o4[1] = f2bf(v.y); o4[2] = f2bf(v.z); o4[3] = f2bf(v.w);
        *(u16x4*)(out + i) = o4;
    }
}

// ---------------- NT GEMM: C[M,N] = A[M,K] * B[N,K]^T  (m97 recipe, no swizzle) ----------------
template<int OUTBF>
__global__ __launch_bounds__(256) void gemm_nt(const u16* __restrict__ A, const u16* __restrict__ B,
                                               void* __restrict__ C, int M, int N, int K) {
    __shared__ u16 As[128 * 32];
    __shared__ u16 Bs[128 * 32];
    const int tid = threadIdx.x;
    const int lane = tid & 63, w = tid >> 6;
    const int quad = lane >> 4, m16 = lane & 15;
    const int wm = w & 1, wn = w >> 1;
    const int r4 = tid >> 2, c8 = (tid & 3) * 8;
    const long arow = (long)blockIdx.x * 128;
    const long brow = (long)blockIdx.y * 128;

    f32x4 acc[4][4];
#pragma unroll
    for (int i = 0; i < 4; i++)
#pragma unroll
        for (int j = 0; j < 4; j++) acc[i][j] = (f32x4){0.f, 0.f, 0.f, 0.f};

    const u16* Ag = A + (arow + r4) * (long)K + c8;
    const u16* Bg = B + (brow + r4) * (long)K + c8;

    for (int k0 = 0; k0 < K; k0 += 32) {
        __syncthreads();
        gload_lds16(Ag + k0,                 (char*)As + tid * 16);
        gload_lds16(Ag + 64l * K + k0,       (char*)As + 4096 + tid * 16);
        gload_lds16(Bg + k0,                 (char*)Bs + tid * 16);
        gload_lds16(Bg + 64l * K + k0,       (char*)Bs + 4096 + tid * 16);
        __syncthreads();
        bf16x8 af[4], bfr[4];
#pragma unroll
        for (int mi = 0; mi < 4; mi++)
            af[mi] = *(const bf16x8*)(As + (wm * 64 + mi * 16 + m16) * 32 + quad * 8);
#pragma unroll
        for (int ni = 0; ni < 4; ni++)
            bfr[ni] = *(const bf16x8*)(Bs + (wn * 64 + ni * 16 + m16) * 32 + quad * 8);
#pragma unroll
        for (int mi = 0; mi < 4; mi++)
#pragma unroll
            for (int ni = 0; ni < 4; ni++)
                acc[mi][ni] = __builtin_amdgcn_mfma_f32_16x16x32_bf16(af[mi], bfr[ni], acc[mi][ni], 0, 0, 0);
    }
#pragma unroll
    for (int mi = 0; mi < 4; mi++) {
#pragma unroll
        for (int ni = 0; ni < 4; ni++) {
            long col = brow + wn * 64 + ni * 16 + m16;
#pragma unroll
            for (int r = 0; r < 4; r++) {
                long row = arow + wm * 64 + mi * 16 + quad * 4 + r;
                float v = acc[mi][ni][r];
                if (OUTBF) ((u16*)C)[row * N + col] = f2bf(v);
                else       ((float*)C)[row * N + col] = v;
            }
        }
    }
}

// ---------------- RoPE + cache scatter ----------------
__global__ __launch_bounds__(256) void rope_scatter(u16* __restrict__ qkv, const float* __restrict__ cosb,
        const float* __restrict__ sinb, const int* __restrict__ slots,
        u16* __restrict__ kb, float* __restrict__ kc, float* __restrict__ vc) {
    const int t = blockIdx.x, tid = threadIdx.x;
    const long qbase = (long)t * NQKV;
#pragma unroll
    for (int i = 0; i < 4; i++) {
        int idx = tid + i * 256;            // 0..1023 : 8 heads x 128 pairs
        int head = idx >> 7, d = idx & 127;
        long off = qbase + head * DH + d;
        float q1 = bf2f(qkv[off]), q2 = bf2f(qkv[off + 128]);
        float c = cosb[(long)t * 128 + d], s = sinb[(long)t * 128 + d];
        qkv[off]       = f2bf((q1 * c - q2 * s) * 0.0625f);
        qkv[off + 128] = f2bf((q2 * c + q1 * s) * 0.0625f);
    }
    const int slot = slots[t];
    if (tid < 128) {
        int d = tid;
        long off = qbase + HN * DH + d;
        float k1 = bf2f(qkv[off]), k2 = bf2f(qkv[off + 128]);
        float c = cosb[(long)t * 128 + d], s = sinb[(long)t * 128 + d];
        float kn1 = k1 * c - k2 * s, kn2 = k2 * c + k1 * s;
        kb[(long)t * DH + d]       = f2bf(kn1);
        kb[(long)t * DH + d + 128] = f2bf(kn2);
        kc[(long)slot * DH + d]       = kn1;
        kc[(long)slot * DH + d + 128] = kn2;
    }
    {
        int d = tid;
        vc[(long)slot * DH + d] = bf2f(qkv[qbase + (HN + 1) * DH + d]);
    }
}

// ---------------- V transpose: qkv v-slice -> vbt[b][d][s] (LDS tile transpose) ----------------
__global__ __launch_bounds__(256) void transpose_v(const u16* __restrict__ qkv, u16* __restrict__ vbt) {
    __shared__ u16 Ls[64][66];   // pad 66: odd dword stride spreads the transpose reads
    const int tid = threadIdx.x;
    const int s0 = blockIdx.x * 64, d0 = blockIdx.y * 64, b = blockIdx.z;
    const int lr = tid >> 3, lc = (tid & 7) * 8;
#pragma unroll
    for (int i = 0; i < 2; i++) {
        int s = s0 + i * 32 + lr;
        u16x8 v = *(const u16x8*)(qkv + (long)(b * SS + s) * NQKV + (HN + 1) * DH + d0 + lc);
        *(u16x8*)(&Ls[i * 32 + lr][lc]) = v;
    }
    __syncthreads();
#pragma unroll
    for (int i = 0; i < 2; i++) {
        int d = i * 32 + lr;
        u16x8 v;
#pragma unroll
        for (int e = 0; e < 8; e++) v[e] = Ls[lc + e][d];
        *(u16x8*)(vbt + ((long)b * DH + d0 + d) * SS + s0 + lc) = v;
    }
}

// ---------------- Flash attention (causal, GQA KV=1) ----------------
// R5 geometry (proven 212us): block = (b, h, 64 q rows), 4 waves x 16 rows, kv-tile 32,
// serial gload_lds staging (the per-tile wait is the sync rail that keeps the 8 heads
// sharing each K/V tile co-temporal in L2 -- R6 showed prefetch drift = 9x HBM fetch),
// 4 blocks/CU, XCD-balanced qb remap. Swapped QK^T + permuted K staging (R5 derivation):
// P->PV A-frag is fully in-lane (4 v_cvt_pk_bf16_f32), no LDS round-trip.
// R8: SPLIT staging wait. Issue 4 K-loads then 4 V-loads; vmcnt(4)+s_barrier exposes only
// K-latency before QK^T; V completes under QK/softmax; vmcnt(0)+s_barrier before PV.
// Per-wave counted wait before raw barrier is sound: each wave drains its OWN 4 loads,
// so after the barrier all waves' loads of that class are complete.
__global__ __launch_bounds__(256, 4) void flash_attn(const u16* __restrict__ qkv, const u16* __restrict__ kb,
                                                     const u16* __restrict__ vbt, u16* __restrict__ attn) {
    __shared__ u16 Ks[32 * 256];      // 16 KB (row-permuted + granule-swizzled)
    __shared__ u16 Vt[256 * 32];      // 16 KB (granule-swizzled)
    const int tid = threadIdx.x;
    const int lane = tid & 63, w = tid >> 6;
    const int quad = lane >> 4, m16 = lane & 15;
    const int xr = blockIdx.x & 7, xt = blockIdx.x >> 3;
    const int qb = (xt == 0) ? 31 - xr : (xt == 1) ? 16 + xr : (xt == 2) ? 15 - xr : xr;
    const int h = blockIdx.y, b = blockIdx.z;
    const int qrow_w = qb * 64 + w * 16;

    // staging decomposition. K: LDS row s = i*8 + krow, src row = kv0 + perm(s):
    //   perm(s) = ((i&1)<<4) + ((krow>>2)<<3) + ((i>>1)<<2) + (krow&3)
    const int krow = tid >> 5, kg = tid & 31, kgs = kg ^ krow;
    const int ks_hi = (krow >> 2) << 3, ks_lo = krow & 3;
    const int vrow = tid >> 2, vg = tid & 3,  vgs = vg ^ ((vrow >> 1) & 3);
    const int km7 = m16 & 7;
    const int vcol = (quad ^ ((m16 >> 1) & 3)) * 8;

    bf16x8 aq[8];
    {
        const u16* qp = qkv + (long)(b * SS + qrow_w + m16) * NQKV + h * DH;
#pragma unroll
        for (int ks = 0; ks < 8; ks++)
            aq[ks] = *(const bf16x8*)(qp + ks * 32 + quad * 8);
    }
    f32x4 o[16];
#pragma unroll
    for (int i = 0; i < 16; i++) o[i] = (f32x4){0.f, 0.f, 0.f, 0.f};
    float m_run = -1e30f;   // running max for q row = m16 (row-uniform across quads)
    float l_run = 0.f;      // per-lane partial sum for q row = m16
    const long kvrow0 = (long)b * SS;
    const u16* vbase = vbt + (long)b * DH * SS;
    const int ntiles = 2 * qb + 2;

    for (int it = 0; it < ntiles; it++) {
        const int kv0 = it * 32;
        __syncthreads();   // all waves done reading previous tile's LDS
#pragma unroll
        for (int i = 0; i < 4; i++) {
            const int srcrow = ((i & 1) << 4) + ks_hi + ((i >> 1) << 2) + ks_lo;  // perm(i*8+krow)
            gload_lds16(kb + (kvrow0 + kv0 + srcrow) * DH + kgs * 8,
                        (char*)Ks + i * 4096 + tid * 16);
        }
#pragma unroll
        for (int i = 0; i < 4; i++) {
            gload_lds16(vbase + (long)(i * 64 + vrow) * SS + kv0 + vgs * 8,
                        (char*)Vt + i * 4096 + tid * 16);
        }
        asm volatile("s_waitcnt vmcnt(4)" ::: "memory");   // own K loads done
        __builtin_amdgcn_s_barrier();                      // all waves' K visible
        __builtin_amdgcn_sched_barrier(0);

        const bool active = (kv0 <= qrow_w + 15);   // wave-uniform
        union { u32 w4[4]; bf16x8 v; } pu;
        if (active) {
            // swapped Q K^T : D[kv][q], lane holds q=m16, kv = n*16+quad*4+r (LDS-row space)
            f32x4 sc[2];
            sc[0] = (f32x4){0.f, 0.f, 0.f, 0.f};
            sc[1] = (f32x4){0.f, 0.f, 0.f, 0.f};
            __builtin_amdgcn_s_setprio(1);
#pragma unroll
            for (int ks = 0; ks < 8; ks++)
#pragma unroll
                for (int n = 0; n < 2; n++) {
                    bf16x8 kf = *(const bf16x8*)(Ks + (n * 16 + m16) * 256 + (((ks * 4 + quad) ^ km7) << 3));
                    sc[n] = __builtin_amdgcn_mfma_f32_16x16x32_bf16(kf, aq[ks], sc[n], 0, 0, 0);
                }
            __builtin_amdgcn_s_setprio(0);
            // causal mask: actual kv = kv0 + quad*8 + n*4 + r (perm-staged); q = qrow_w + m16
            if (kv0 >= qb * 64) {
                const int qg = qrow_w + m16;
                const int kvb = kv0 + quad * 8;
#pragma unroll
                for (int n = 0; n < 2; n++)
#pragma unroll
                    for (int r = 0; r < 4; r++)
                        if (kvb + n * 4 + r > qg) sc[n][r] = -1e30f;
            }
            // online softmax, defer-max (thr=8): per-lane 8 values of row q=m16
            float mx = fmaxf(fmaxf(fmaxf(sc[0][0], sc[0][1]), fmaxf(sc[0][2], sc[0][3])),
                             fmaxf(fmaxf(sc[1][0], sc[1][1]), fmaxf(sc[1][2], sc[1][3])));
            if (__any((int)(mx > m_run + 8.f))) {   // slow path: first tile + rare growth
                float mr = fmaxf(mx, __shfl_xor(mx, 16));
                mr = fmaxf(mr, __shfl_xor(mr, 32));
                float mn = fmaxf(m_run, mr);
                float alpha = __expf(m_run - mn);   // row-uniform (for q=m16)
                m_run = mn;
                l_run *= alpha;
                float ar[4];
#pragma unroll
                for (int r = 0; r < 4; r++) ar[r] = __shfl(alpha, quad * 4 + r);  // o rows = quad*4+r
#pragma unroll
                for (int nf = 0; nf < 16; nf++)
#pragma unroll
                    for (int r = 0; r < 4; r++) o[nf][r] *= ar[r];
            }
#pragma unroll
            for (int n = 0; n < 2; n++)
#pragma unroll
                for (int r = 0; r < 4; r++) {
                    float p = __expf(sc[n][r] - m_run);   // bounded by e^8
                    sc[n][r] = p;
                    l_run += p;
                }
            // P -> PV A-frag: in-lane pack (element e = n*4+r matches kv = quad*8+e)
            pu.w4[0] = cvtpk_bf16(sc[0][0], sc[0][1]);
            pu.w4[1] = cvtpk_bf16(sc[0][2], sc[0][3]);
            pu.w4[2] = cvtpk_bf16(sc[1][0], sc[1][1]);
            pu.w4[3] = cvtpk_bf16(sc[1][2], sc[1][3]);
        }
        asm volatile("s_waitcnt vmcnt(0)" ::: "memory");   // own V loads done
        __builtin_amdgcn_s_barrier();                      // all waves' V visible
        __builtin_amdgcn_sched_barrier(0);
        if (active) {
            __builtin_amdgcn_s_setprio(1);
#pragma unroll
            for (int nf = 0; nf < 16; nf++) {
                bf16x8 vf = *(const bf16x8*)(Vt + (nf * 16 + m16) * 32 + vcol);
                o[nf] = __builtin_amdgcn_mfma_f32_16x16x32_bf16(pu.v, vf, o[nf], 0, 0, 0);
            }
            __builtin_amdgcn_s_setprio(0);
        }
    }
    // final: reduce per-lane l partials across quads (row q=m16), then bcast to o rows
    l_run += __shfl_xor(l_run, 16);
    l_run += __shfl_xor(l_run, 32);
    float invm = 1.f / l_run;
    float ir[4];
#pragma unroll
    for (int r = 0; r < 4; r++) ir[r] = __shfl(invm, quad * 4 + r);
#pragma unroll
    for (int nf = 0; nf < 16; nf++)
#pragma unroll
        for (int r = 0; r < 4; r++) {
            long row = (long)(b * SS + qrow_w + quad * 4 + r);
            attn[row * (HN * DH) + h * DH + nf * 16 + m16] = f2bf(o[nf][r] * ir[r]);
        }
}

// ---------------- launch ----------------
extern "C" void kernel_launch(void* const* d_in, const int* in_sizes, int n_in,
                              void* d_out, int out_size, void* d_ws, size_t ws_size,
                              hipStream_t stream) {
    (void)in_sizes; (void)n_in; (void)out_size; (void)ws_size;
    const float* hidden = (const float*)d_in[0];
    const float* cosb   = (const float*)d_in[1];
    const float* sinb   = (const float*)d_in[2];
    const int*   slots  = (const int*)d_in[3];
    const float* kc_in  = (const float*)d_in[4];
    const float* vc_in  = (const float*)d_in[5];
    const float* w_qkv  = (const float*)d_in[6];
    const float* w_o    = (const float*)d_in[7];

    float* out    = (float*)d_out;
    float* kc_out = out + (size_t)TT * HID;
    float* vc_out = kc_out + (size_t)NSLOTS * DH;

    char* p = (char*)d_ws;
    u16* hid_b  = (u16*)p;  p += (size_t)TT * HID * 2;     // 33.6 MB
    u16* wqkv_b = (u16*)p;  p += (size_t)NQKV * HID * 2;   // 10.5 MB
    u16* wo_b   = (u16*)p;  p += (size_t)HID * HID * 2;    // 8.4 MB
    u16* kb     = (u16*)p;  p += (size_t)TT * DH * 2;      // 4.2 MB
    u16* vbt    = (u16*)p;  p += (size_t)TT * DH * 2;      // 4.2 MB  [b][d][s]
    u16* attn_b = hid_b;                 // hid_b dead after GEMM1
    u16* qkv_b  = (u16*)d_out;           // out region scratch; dead before GEMM2 writes

    hipMemcpyAsync(kc_out, kc_in, (size_t)NSLOTS * DH * 4, hipMemcpyDeviceToDevice, stream);
    hipMemcpyAsync(vc_out, vc_in, (size_t)NSLOTS * DH * 4, hipMemcpyDeviceToDevice, stream);

    cvt_f32_bf16<<<dim3(2048), dim3(256), 0, stream>>>(hidden, hid_b, (long)TT * HID);
    cvt_f32_bf16<<<dim3(640),  dim3(256), 0, stream>>>(w_qkv, wqkv_b, (long)NQKV * HID);
    cvt_f32_bf16<<<dim3(512),  dim3(256), 0, stream>>>(w_o,   wo_b,   (long)HID * HID);

    gemm_nt<1><<<dim3(TT / 128, NQKV / 128), dim3(256), 0, stream>>>(hid_b, wqkv_b, qkv_b, TT, NQKV, HID);
    rope_scatter<<<dim3(TT), dim3(256), 0, stream>>>(qkv_b, cosb, sinb, slots, kb, kc_out, vc_out);
    transpose_v<<<dim3(SS / 64, DH / 64, BB), dim3(256), 0, stream>>>(qkv_b, vbt);
    flash_attn<<<dim3(SS / 64, HN, BB), dim3(256), 0, stream>>>(qkv_b, kb, vbt, attn_b);
    gemm_nt<0><<<dim3(TT / 128, HID / 128), dim3(256), 0, stream>>>(attn_b, wo_b, out, TT, HID, HID);
}